// Round 7
// baseline (196.839 us; speedup 1.0000x reference)
//
#include <hip/hip_runtime.h>
#include <hip/hip_bf16.h>
#include <stdint.h>

typedef __attribute__((ext_vector_type(8))) short short8;
typedef __attribute__((ext_vector_type(4))) float f32x4;

#define BIGF 1e9f
#define MAXM 96                  // max genuine members per pid (λ≈16, safe)

__device__ inline float blo(unsigned int u) {
    union { unsigned int i; float f; } v; v.i = u << 16; return v.f;
}
__device__ inline float bhi(unsigned int u) {
    union { unsigned int i; float f; } v; v.i = u & 0xffff0000u; return v.f;
}
__device__ inline unsigned int fkey(float s) {   // order-preserving uint encode
    unsigned int b = __float_as_uint(s);
    return (b & 0x80000000u) ? ~b : (b | 0x80000000u);
}
__device__ inline float funkey(unsigned int k) {
    unsigned int b = (k & 0x80000000u) ? (k & 0x7fffffffu) : ~k;
    return __uint_as_float(b);
}
__device__ inline void async16(const unsigned short* g, unsigned short* l) {
    __builtin_amdgcn_global_load_lds(
        (const __attribute__((address_space(1))) void*)g,
        (__attribute__((address_space(3))) void*)l, 16, 0, 0);
}
__device__ inline unsigned short f2b(float x) {
    __hip_bfloat16 h = __float2bfloat16(x);
    return *reinterpret_cast<unsigned short*>(&h);
}

// ---------------------------------------------------------------------------
// Kernel 1 (fused prep): blocks [0, N/4): L2-normalize 4 rows each -> bf16
// normed + gpid; write hp=BIGF for NON-genuine rows; zero hn/mb key arrays
// and the done counter. Blocks [N/4, N/4+256): hardest-positive for one pid,
// normalizing its ~16 member rows directly from raw emb (identical bf16
// rounding as the normalize path -> consistent numerics with pass2).
// The two block families write disjoint outputs -> no grid sync needed.
// ---------------------------------------------------------------------------
__global__ __launch_bounds__(256) void k_prep(
    const float* __restrict__ emb, const int* __restrict__ labels,
    const int* __restrict__ pids, unsigned short* __restrict__ normed,
    int* __restrict__ gpid, float* __restrict__ hp_out,
    unsigned int* __restrict__ hn_key, unsigned int* __restrict__ mb_key,
    int* __restrict__ done, int N)
{
    __shared__ int list[MAXM];
    __shared__ unsigned int hp_loc[MAXM];
    __shared__ unsigned short rows[MAXM * 256];   // 48 KB
    __shared__ int cnt;

    const int b = blockIdx.x;
    const int t = threadIdx.x;
    const int nblk = N / 4;              // 2048 normalize blocks
    const int w = t >> 6, lane = t & 63;

    if (b < nblk) {
        // ---- init scratch (stream-ordered before k_pass2 uses it) ----
        if (b == 0 && t == 0) *done = 0;
        if (b < 32) hn_key[b * 256 + t] = 0u;          // 32*256 = 8192
        else if (b < 64) mb_key[(b - 32) * 256 + t] = 0u;

        // ---- normalize 4 rows (one per wave) ----
        int row = b * 4 + w;
        const float4* src = (const float4*)(emb + ((size_t)row << 8));
        float4 x = src[lane];
        float ss = x.x * x.x + x.y * x.y + x.z * x.z + x.w * x.w;
        #pragma unroll
        for (int off = 32; off >= 1; off >>= 1) ss += __shfl_xor(ss, off, 64);
        float inv = 1.0f / fmaxf(sqrtf(ss), 1e-12f);
        ushort4 o;
        o.x = f2b(x.x * inv); o.y = f2b(x.y * inv);
        o.z = f2b(x.z * inv); o.w = f2b(x.w * inv);
        ((ushort4*)(normed + ((size_t)row << 8)))[lane] = o;
        if (lane == 0) {
            int genuine = (labels[row] == 1);
            gpid[row] = genuine ? pids[row] : -1;
            if (!genuine) hp_out[row] = BIGF;   // pid-blocks own genuine rows
        }
        return;
    }

    // ---- hardest positive for pid p ----
    int p = b - nblk;
    if (t == 0) cnt = 0;
    __syncthreads();
    for (int j = t; j < N; j += 256)
        if (pids[j] == p && labels[j] == 1) {
            int idx = atomicAdd(&cnt, 1);
            if (idx < MAXM) list[idx] = j;
        }
    __syncthreads();
    int M = min(cnt, MAXM);
    for (int s = t; s < M; s += 256) hp_loc[s] = 0xFFFFFFFFu;
    // normalize member rows from raw emb into LDS (one wave per row)
    for (int mi = w; mi < M; mi += 4) {
        const float4* src = (const float4*)(emb + ((size_t)list[mi] << 8));
        float4 x = src[lane];
        float ss = x.x * x.x + x.y * x.y + x.z * x.z + x.w * x.w;
        #pragma unroll
        for (int off = 32; off >= 1; off >>= 1) ss += __shfl_xor(ss, off, 64);
        float inv = 1.0f / fmaxf(sqrtf(ss), 1e-12f);
        ushort4 o;
        o.x = f2b(x.x * inv); o.y = f2b(x.y * inv);
        o.z = f2b(x.z * inv); o.w = f2b(x.w * inv);
        ((ushort4*)&rows[mi * 256])[lane] = o;
    }
    __syncthreads();
    for (int pr = t; pr < M * M; pr += 256) {
        int i = pr / M, j = pr - i * M;
        if (i == j) continue;
        const uint4* ap = (const uint4*)&rows[i * 256];
        const uint4* bp = (const uint4*)&rows[j * 256];
        float s = 0.f;
        #pragma unroll 4
        for (int k = 0; k < 32; ++k) {
            uint4 a = ap[k], bb = bp[k];
            s += blo(a.x) * blo(bb.x) + bhi(a.x) * bhi(bb.x);
            s += blo(a.y) * blo(bb.y) + bhi(a.y) * bhi(bb.y);
            s += blo(a.z) * blo(bb.z) + bhi(a.z) * bhi(bb.z);
            s += blo(a.w) * blo(bb.w) + bhi(a.w) * bhi(bb.w);
        }
        atomicMin(&hp_loc[i], fkey(s));
    }
    __syncthreads();
    for (int s = t; s < M; s += 256) {
        unsigned int key = hp_loc[s];
        hp_out[list[s]] = (key == 0xFFFFFFFFu) ? BIGF : funkey(key);
    }
}

// ---------------------------------------------------------------------------
// Kernel 2: symmetric MFMA pass, exact triangular 1-D launch (2080 blocks).
// Epilogue reduces straight into two 32 KB global uint-key arrays via
// device-scope atomicMax (no 4 MB partial arrays -> no L2 thrash).
// The last-finishing block (done counter) computes the final loss scalar,
// reading the key arrays with atomic-reads (cross-XCD coherent).
// ---------------------------------------------------------------------------
__global__ __launch_bounds__(256) void k_pass2(
    const unsigned short* __restrict__ normed, const int* __restrict__ pids,
    const int* __restrict__ gpid, const float* __restrict__ hp,
    const int* __restrict__ labels,
    unsigned int* __restrict__ hn_key, unsigned int* __restrict__ mb_key,
    int* __restrict__ done, float* __restrict__ out, int N)
{
    // triangle decode: row rt holds (64-rt) blocks (ct>=rt).
    const int b = blockIdx.x;
    int rt = (int)floorf((129.0f - sqrtf(16641.0f - 8.0f * (float)b)) * 0.5f);
    rt = min(rt, 63);
    while (64 * (rt + 1) - ((rt + 1) * rt) / 2 <= b) ++rt;
    while (64 * rt - (rt * (rt - 1)) / 2 > b) --rt;
    const int ct = rt + (b - (64 * rt - (rt * (rt - 1)) / 2));
    const bool diag = (ct == rt);

    __shared__ unsigned short As[2][128 * 32];
    __shared__ unsigned short Bs[2][128 * 32];
    __shared__ float hp_r[128], hp_c[128];
    __shared__ int pid_r[128], gpid_r[128], pid_c[128], gpid_c[128];
    __shared__ int amlast;
    __shared__ float rs[4], rc[4];

    const int t = threadIdx.x;
    const int lane = t & 63;
    const int w = t >> 6;
    const int wr = w & 1, wc = w >> 1;
    const int quad = lane >> 4, l16 = lane & 15;
    const int rbase = rt * 128, cbase = ct * 128;

    if (t < 128) {
        hp_r[t] = hp[rbase + t];
        pid_r[t] = pids[rbase + t];
        gpid_r[t] = gpid[rbase + t];
        hp_c[t] = hp[cbase + t];
        pid_c[t] = pids[cbase + t];
        gpid_c[t] = gpid[cbase + t];
    }

    // staging: LDS chunk cid in {t, t+256}; row = cid>>2, pos = cid&3.
    // LDS pos holds global 16B chunk c = pos ^ ((row>>1)&3)  (bank swizzle).
    const int r0 = t >> 2, p0 = t & 3;
    const int c0 = p0 ^ ((r0 >> 1) & 3);
    const unsigned short* gA0 = normed + ((size_t)(rbase + r0) << 8) + c0 * 8;
    const unsigned short* gA1 = normed + ((size_t)(rbase + r0 + 64) << 8) + c0 * 8;
    const unsigned short* gB0 = normed + ((size_t)(cbase + r0) << 8) + c0 * 8;
    const unsigned short* gB1 = normed + ((size_t)(cbase + r0 + 64) << 8) + c0 * 8;

    async16(gA0, &As[0][t * 8]);
    async16(gA1, &As[0][2048 + t * 8]);
    if (!diag) {
        async16(gB0, &Bs[0][t * 8]);
        async16(gB1, &Bs[0][2048 + t * 8]);
    }

    f32x4 acc[4][4];
    #pragma unroll
    for (int mt = 0; mt < 4; ++mt)
        #pragma unroll
        for (int nt = 0; nt < 4; ++nt)
            acc[mt][nt] = (f32x4){0.f, 0.f, 0.f, 0.f};

    const int sw = (l16 >> 1) & 3;
    const int aoff = (wr * 64 + l16) * 32 + (quad ^ sw) * 8;   // + mt*512
    const int boff = (wc * 64 + l16) * 32 + (quad ^ sw) * 8;   // + nt*512

    const unsigned short* Bbase[2] = { diag ? &As[0][0] : &Bs[0][0],
                                       diag ? &As[1][0] : &Bs[1][0] };

    for (int kb = 0; kb < 8; ++kb) {
        __syncthreads();
        int cur = kb & 1;
        if (kb < 7) {
            int nxt = cur ^ 1;
            int ko = (kb + 1) << 5;
            async16(gA0 + ko, &As[nxt][t * 8]);
            async16(gA1 + ko, &As[nxt][2048 + t * 8]);
            if (!diag) {
                async16(gB0 + ko, &Bs[nxt][t * 8]);
                async16(gB1 + ko, &Bs[nxt][2048 + t * 8]);
            }
        }
        short8 af[4], bf[4];
        #pragma unroll
        for (int mt = 0; mt < 4; ++mt)
            af[mt] = *reinterpret_cast<const short8*>(&As[cur][aoff + mt * 512]);
        #pragma unroll
        for (int nt = 0; nt < 4; ++nt)
            bf[nt] = *reinterpret_cast<const short8*>(&Bbase[cur][boff + nt * 512]);
        #pragma unroll
        for (int mt = 0; mt < 4; ++mt)
            #pragma unroll
            for (int nt = 0; nt < 4; ++nt)
                acc[mt][nt] = __builtin_amdgcn_mfma_f32_16x16x32_bf16(
                    af[mt], bf[nt], acc[mt][nt], 0, 0, 0);
    }

    // ---- normal epilogue: anchors = rows; global atomicMax reduce ----
    // C layout: row = mt*16+quad*4+r (+wr*64), col = nt*16+l16 (+wc*64)
    int gp[4];
    #pragma unroll
    for (int nt = 0; nt < 4; ++nt) gp[nt] = gpid_c[wc * 64 + nt * 16 + l16];
    #pragma unroll
    for (int mt = 0; mt < 4; ++mt) {
        #pragma unroll
        for (int r = 0; r < 4; ++r) {
            int rl = wr * 64 + mt * 16 + quad * 4 + r;
            int prow = pid_r[rl];
            float hprow = hp_r[rl];
            float v1 = -BIGF, v2 = -BIGF;
            #pragma unroll
            for (int nt = 0; nt < 4; ++nt) {
                float s = acc[mt][nt][r];
                float tt = (prow != gp[nt]) ? s : -BIGF;
                v1 = fmaxf(v1, tt);
                float t2 = (tt < hprow) ? tt : -BIGF;
                v2 = fmaxf(v2, t2);
            }
            #pragma unroll
            for (int off = 8; off >= 1; off >>= 1) {
                v1 = fmaxf(v1, __shfl_xor(v1, off, 64));
                v2 = fmaxf(v2, __shfl_xor(v2, off, 64));
            }
            if (l16 == 0) {
                atomicMax(&hn_key[rbase + rl], fkey(v1));
                atomicMax(&mb_key[rbase + rl], fkey(v2));
            }
        }
    }

    // ---- transpose epilogue: anchors = cols (off-diagonal only) ----
    if (!diag) {
        int4 gr[4];
        #pragma unroll
        for (int mt = 0; mt < 4; ++mt)
            gr[mt] = *(const int4*)&gpid_r[wr * 64 + mt * 16 + quad * 4];
        #pragma unroll
        for (int nt = 0; nt < 4; ++nt) {
            int c = wc * 64 + nt * 16 + l16;
            int pc = pid_c[c];
            float hpc = hp_c[c];
            float v1 = -BIGF, v2 = -BIGF;
            #pragma unroll
            for (int mt = 0; mt < 4; ++mt) {
                const int* g = (const int*)&gr[mt];
                #pragma unroll
                for (int r = 0; r < 4; ++r) {
                    float s = acc[mt][nt][r];
                    float tt = (pc != g[r]) ? s : -BIGF;
                    v1 = fmaxf(v1, tt);
                    float t2 = (tt < hpc) ? tt : -BIGF;
                    v2 = fmaxf(v2, t2);
                }
            }
            v1 = fmaxf(v1, __shfl_xor(v1, 16, 64));
            v1 = fmaxf(v1, __shfl_xor(v1, 32, 64));
            v2 = fmaxf(v2, __shfl_xor(v2, 16, 64));
            v2 = fmaxf(v2, __shfl_xor(v2, 32, 64));
            if (quad == 0) {
                atomicMax(&hn_key[cbase + c], fkey(v1));
                atomicMax(&mb_key[cbase + c], fkey(v2));
            }
        }
    }

    // ---- last-finisher computes the loss scalar ----
    if (t == 0) {
        __threadfence();
        amlast = (atomicAdd(done, 1) == (int)gridDim.x - 1);
    }
    __syncthreads();
    if (!amlast) return;

    float lsum = 0.f, lcnt = 0.f;
    for (int i = t; i < N; i += 256) {
        // atomic-reads: device-scope coherent view of the key arrays
        float hn_all = funkey(atomicMax(&hn_key[i], 0u));
        float mb = funkey(atomicMax(&mb_key[i], 0u));
        float hpv = hp[i];
        bool valid = (labels[i] == 1) && (hpv < 1e8f) && (hn_all > -1e8f);
        float hn = (mb > hpv - 0.5f) ? mb : hn_all;
        float base = fmaxf(hn - hpv + 0.5f, 0.f);
        float wgt = (hpv < 0.6f || hn > 0.3f) ? 2.f : 1.f;
        float loss = base * wgt + 0.5f * (1.f - hpv) + 0.5f * fmaxf(hn + 0.2f, 0.f);
        if (valid) { lsum += loss; lcnt += 1.f; }
    }
    #pragma unroll
    for (int off = 32; off >= 1; off >>= 1) {
        lsum += __shfl_xor(lsum, off, 64);
        lcnt += __shfl_xor(lcnt, off, 64);
    }
    if (lane == 0) { rs[w] = lsum; rc[w] = lcnt; }
    __syncthreads();
    if (t == 0) {
        float S = rs[0] + rs[1] + rs[2] + rs[3];
        float C = rc[0] + rc[1] + rc[2] + rc[3];
        out[0] = (C > 0.f) ? S / fmaxf(C, 1.f) : 0.f;
    }
}

extern "C" void kernel_launch(void* const* d_in, const int* in_sizes, int n_in,
                              void* d_out, int out_size, void* d_ws, size_t ws_size,
                              hipStream_t stream)
{
    const float* emb = (const float*)d_in[0];
    const int* labels = (const int*)d_in[1];
    const int* pids = (const int*)d_in[2];
    float* out = (float*)d_out;
    int N = in_sizes[1];          // 8192

    char* ws = (char*)d_ws;
    unsigned short* normed = (unsigned short*)ws;  ws += (size_t)N * 256 * 2;  // 4 MB
    int* gpid = (int*)ws;                          ws += (size_t)N * 4;
    float* hp = (float*)ws;                        ws += (size_t)N * 4;
    unsigned int* hn_key = (unsigned int*)ws;      ws += (size_t)N * 4;   // 32 KB
    unsigned int* mb_key = (unsigned int*)ws;      ws += (size_t)N * 4;   // 32 KB
    int* done = (int*)ws;                          ws += 4;

    int M = N / 128;                         // 64 tiles
    int tri = M * (M + 1) / 2;               // 2080 blocks

    k_prep<<<N / 4 + 256, 256, 0, stream>>>(emb, labels, pids, normed, gpid,
                                            hp, hn_key, mb_key, done, N);
    k_pass2<<<tri, 256, 0, stream>>>(normed, pids, gpid, hp, labels,
                                     hn_key, mb_key, done, out, N);
}

// Round 8
// 153.195 us; speedup vs baseline: 1.2849x; 1.2849x over previous
//
#include <hip/hip_runtime.h>
#include <hip/hip_bf16.h>
#include <stdint.h>

typedef __attribute__((ext_vector_type(8))) short short8;
typedef __attribute__((ext_vector_type(4))) float f32x4;

#define BIGF 1e9f
#define NSLOT 4                  // col splits
#define MAXM 96                  // max genuine members per pid (λ≈16, safe)

__device__ inline float blo(unsigned int u) {
    union { unsigned int i; float f; } v; v.i = u << 16; return v.f;
}
__device__ inline float bhi(unsigned int u) {
    union { unsigned int i; float f; } v; v.i = u & 0xffff0000u; return v.f;
}
__device__ inline unsigned int fkey(float s) {   // order-preserving uint encode
    unsigned int b = __float_as_uint(s);
    return (b & 0x80000000u) ? ~b : (b | 0x80000000u);
}
__device__ inline float funkey(unsigned int k) {
    unsigned int b = (k & 0x80000000u) ? (k & 0x7fffffffu) : ~k;
    return __uint_as_float(b);
}
__device__ inline void async16(const unsigned short* g, unsigned short* l) {
    __builtin_amdgcn_global_load_lds(
        (const __attribute__((address_space(1))) void*)g,
        (__attribute__((address_space(3))) void*)l, 16, 0, 0);
}
__device__ inline unsigned short f2b(float x) {
    __hip_bfloat16 h = __float2bfloat16(x);
    return *reinterpret_cast<unsigned short*>(&h);
}

// ---------------------------------------------------------------------------
// Kernel 1 (fused prep): blocks [0, N/4): normalize 4 rows -> bf16 normed +
// gpid; hp=BIGF for non-genuine rows; block 0 zeroes gred/done.
// Blocks [N/4, N/4+256): hardest positive for one pid (members normalized
// from raw emb with identical bf16 rounding; M^2 LDS dots).
// ---------------------------------------------------------------------------
__global__ __launch_bounds__(256) void k_prep(
    const float* __restrict__ emb, const int* __restrict__ labels,
    const int* __restrict__ pids, unsigned short* __restrict__ normed,
    int* __restrict__ gpid, float* __restrict__ hp_out,
    float* __restrict__ gred, int* __restrict__ done, int N)
{
    __shared__ int list[MAXM];
    __shared__ unsigned int hp_loc[MAXM];
    __shared__ unsigned short rows[MAXM * 256];   // 48 KB
    __shared__ int cnt;

    const int b = blockIdx.x;
    const int t = threadIdx.x;
    const int nblk = N / 4;
    const int w = t >> 6, lane = t & 63;

    if (b < nblk) {
        if (b == 0 && t < 3) {
            if (t < 2) gred[t] = 0.f;
            else *done = 0;
        }
        int row = b * 4 + w;
        const float4* src = (const float4*)(emb + ((size_t)row << 8));
        float4 x = src[lane];
        float ss = x.x * x.x + x.y * x.y + x.z * x.z + x.w * x.w;
        #pragma unroll
        for (int off = 32; off >= 1; off >>= 1) ss += __shfl_xor(ss, off, 64);
        float inv = 1.0f / fmaxf(sqrtf(ss), 1e-12f);
        ushort4 o;
        o.x = f2b(x.x * inv); o.y = f2b(x.y * inv);
        o.z = f2b(x.z * inv); o.w = f2b(x.w * inv);
        ((ushort4*)(normed + ((size_t)row << 8)))[lane] = o;
        if (lane == 0) {
            int genuine = (labels[row] == 1);
            gpid[row] = genuine ? pids[row] : -1;
            if (!genuine) hp_out[row] = BIGF;
        }
        return;
    }

    int p = b - nblk;
    if (t == 0) cnt = 0;
    __syncthreads();
    for (int j = t; j < N; j += 256)
        if (pids[j] == p && labels[j] == 1) {
            int idx = atomicAdd(&cnt, 1);
            if (idx < MAXM) list[idx] = j;
        }
    __syncthreads();
    int M = min(cnt, MAXM);
    for (int s = t; s < M; s += 256) hp_loc[s] = 0xFFFFFFFFu;
    for (int mi = w; mi < M; mi += 4) {
        const float4* src = (const float4*)(emb + ((size_t)list[mi] << 8));
        float4 x = src[lane];
        float ss = x.x * x.x + x.y * x.y + x.z * x.z + x.w * x.w;
        #pragma unroll
        for (int off = 32; off >= 1; off >>= 1) ss += __shfl_xor(ss, off, 64);
        float inv = 1.0f / fmaxf(sqrtf(ss), 1e-12f);
        ushort4 o;
        o.x = f2b(x.x * inv); o.y = f2b(x.y * inv);
        o.z = f2b(x.z * inv); o.w = f2b(x.w * inv);
        ((ushort4*)&rows[mi * 256])[lane] = o;
    }
    __syncthreads();
    for (int pr = t; pr < M * M; pr += 256) {
        int i = pr / M, j = pr - i * M;
        if (i == j) continue;
        const uint4* ap = (const uint4*)&rows[i * 256];
        const uint4* bp = (const uint4*)&rows[j * 256];
        float s = 0.f;
        #pragma unroll 4
        for (int k = 0; k < 32; ++k) {
            uint4 a = ap[k], bb = bp[k];
            s += blo(a.x) * blo(bb.x) + bhi(a.x) * bhi(bb.x);
            s += blo(a.y) * blo(bb.y) + bhi(a.y) * bhi(bb.y);
            s += blo(a.z) * blo(bb.z) + bhi(a.z) * bhi(bb.z);
            s += blo(a.w) * blo(bb.w) + bhi(a.w) * bhi(bb.w);
        }
        atomicMin(&hp_loc[i], fkey(s));
    }
    __syncthreads();
    for (int s = t; s < M; s += 256) {
        unsigned int key = hp_loc[s];
        hp_out[list[s]] = (key == 0xFFFFFFFFu) ? BIGF : funkey(key);
    }
}

// ---------------------------------------------------------------------------
// Kernel 2: persistent row-tile MFMA pass. Grid = (N/128)*4 = 256 blocks
// (exactly 1/CU), 512 threads (8 waves: wr 2x64 rows, wc 4x32 cols).
// A-tile (128x256, 64 KB) staged to LDS ONCE; 16 col-tiles swept with a
// double-buffered 8 KB B chunk per kb-step (128-step pipeline/block).
// hnall/mbel persist in registers; one epilogue per block. XOR-swizzled
// LDS placement (conflict-free). Partials: p[split*N + row], NSLOT=4.
// ---------------------------------------------------------------------------
__global__ __launch_bounds__(512, 2) void k_pass2(
    const unsigned short* __restrict__ normed, const int* __restrict__ pids,
    const int* __restrict__ gpid, const float* __restrict__ hp,
    float* __restrict__ p_hn, float* __restrict__ p_mb, int N)
{
    __shared__ unsigned short Afull[128 * 256];   // 64 KB
    __shared__ unsigned short Bs[2][128 * 32];    // 16 KB
    __shared__ float hp_s[128];
    __shared__ int pid_s[128];

    const int t = threadIdx.x;
    const int lane = t & 63;
    const int w = t >> 6;
    const int wr = w & 1, wc = w >> 1;            // wr: 2 row groups, wc: 4 col groups
    const int quad = lane >> 4, l16 = lane & 15;
    const int rt = blockIdx.x >> 2;
    const int split = blockIdx.x & 3;
    const int rbase = rt * 128;
    const int colspan = N >> 2;
    const int cstart = split * colspan;
    const int C = colspan >> 7;                   // 16 col tiles

    if (t < 128) { hp_s[t] = hp[rbase + t]; pid_s[t] = pids[rbase + t]; }

    // staging pattern: thread t -> row t>>2, 16B pos t&3, swizzled source chunk
    const int r0 = t >> 2, p0 = t & 3;
    const int c0 = p0 ^ ((r0 >> 1) & 3);
    const unsigned short* gA = normed + ((size_t)(rbase + r0) << 8) + c0 * 8;
    const unsigned short* gB = normed + ((size_t)(cstart + r0) << 8) + c0 * 8;

    // prologue: full A (8 chunks) + B tile0 chunk0
    #pragma unroll
    for (int kb = 0; kb < 8; ++kb)
        async16(gA + kb * 32, &Afull[kb * 4096 + t * 8]);
    async16(gB, &Bs[0][t * 8]);
    __syncthreads();   // drain prologue; hp_s/pid_s ready

    // register-cache per-row mask scalars: rows rl = wr*64 + mt*16 + quad*4 + r
    int pid_c16[4][4]; float hp_c16[4][4];
    #pragma unroll
    for (int mt = 0; mt < 4; ++mt)
        #pragma unroll
        for (int r = 0; r < 4; ++r) {
            int rl = wr * 64 + mt * 16 + quad * 4 + r;
            pid_c16[mt][r] = pid_s[rl];
            hp_c16[mt][r] = hp_s[rl];
        }

    f32x4 acc[4][2];
    float hnall[4][4], mbel[4][4];
    #pragma unroll
    for (int mt = 0; mt < 4; ++mt)
        #pragma unroll
        for (int r = 0; r < 4; ++r) { hnall[mt][r] = -BIGF; mbel[mt][r] = -BIGF; }
    #pragma unroll
    for (int mt = 0; mt < 4; ++mt)
        #pragma unroll
        for (int nt = 0; nt < 2; ++nt)
            acc[mt][nt] = (f32x4){0.f, 0.f, 0.f, 0.f};

    const int sw = (l16 >> 1) & 3;
    const int aoff = (wr * 64 + l16) * 32 + (quad ^ sw) * 8;   // +mt*512, +kb*4096
    const int boff = (wc * 32 + l16) * 32 + (quad ^ sw) * 8;   // +nt*512

    int buf = 0;
    for (int ti = 0; ti < C; ++ti) {
        const int cbase = cstart + ti * 128;
        // gpid for this tile's columns (consumed at tile end)
        int gp0 = gpid[cbase + wc * 32 + l16];
        int gp1 = gpid[cbase + wc * 32 + 16 + l16];
        const unsigned short* gBt = gB + ((size_t)ti << 15);   // ti*128 rows * 256
        for (int kb = 0; kb < 8; ++kb) {
            __syncthreads();
            int nxt = buf ^ 1;
            if (kb < 7)
                async16(gBt + (kb + 1) * 32, &Bs[nxt][t * 8]);
            else if (ti < C - 1)
                async16(gBt + (1 << 15), &Bs[nxt][t * 8]);
            short8 af[4], bf[2];
            #pragma unroll
            for (int mt = 0; mt < 4; ++mt)
                af[mt] = *reinterpret_cast<const short8*>(
                    &Afull[kb * 4096 + aoff + mt * 512]);
            #pragma unroll
            for (int nt = 0; nt < 2; ++nt)
                bf[nt] = *reinterpret_cast<const short8*>(
                    &Bs[buf][boff + nt * 512]);
            #pragma unroll
            for (int mt = 0; mt < 4; ++mt)
                #pragma unroll
                for (int nt = 0; nt < 2; ++nt)
                    acc[mt][nt] = __builtin_amdgcn_mfma_f32_16x16x32_bf16(
                        af[mt], bf[nt], acc[mt][nt], 0, 0, 0);
            buf = nxt;
        }
        // per-tile accumulate (VALU only; overlaps next tile's prefetch)
        #pragma unroll
        for (int mt = 0; mt < 4; ++mt)
            #pragma unroll
            for (int r = 0; r < 4; ++r) {
                int prow = pid_c16[mt][r];
                float hprow = hp_c16[mt][r];
                float s0 = acc[mt][0][r], s1 = acc[mt][1][r];
                float t0 = (prow != gp0) ? s0 : -BIGF;
                float t1 = (prow != gp1) ? s1 : -BIGF;
                float v1 = fmaxf(t0, t1);
                hnall[mt][r] = fmaxf(hnall[mt][r], v1);
                float u0 = (t0 < hprow) ? t0 : -BIGF;
                float u1 = (t1 < hprow) ? t1 : -BIGF;
                mbel[mt][r] = fmaxf(mbel[mt][r], fmaxf(u0, u1));
                acc[mt][0][r] = 0.f; acc[mt][1][r] = 0.f;
            }
    }

    // block epilogue: reduce across the 16 lanes sharing each row, store
    #pragma unroll
    for (int mt = 0; mt < 4; ++mt) {
        #pragma unroll
        for (int r = 0; r < 4; ++r) {
            float v1 = hnall[mt][r], v2 = mbel[mt][r];
            #pragma unroll
            for (int off = 8; off >= 1; off >>= 1) {
                v1 = fmaxf(v1, __shfl_xor(v1, off, 64));
                v2 = fmaxf(v2, __shfl_xor(v2, off, 64));
            }
            if (l16 == 0) {
                int row = rbase + wr * 64 + mt * 16 + quad * 4 + r;
                // wc 0..3 all hold identical cols? no -- each wc covered
                // different cols; all four must contribute: combine via LDS?
                // They write DIFFERENT col ranges of the same rows -> must
                // merge. Use per-wc slots then merge in k_rowloss:
                p_hn[((size_t)(split * 4 + wc)) * N + row] = v1;
                p_mb[((size_t)(split * 4 + wc)) * N + row] = v2;
            }
        }
    }
}

// ---------------------------------------------------------------------------
// Kernel 3: per-row loss + grid reduce + fused final (last-block pattern).
// 16 slots per row (4 splits x 4 wc groups).
// hn = (mbel > hp - margin) ? mbel : hn_all   (hn_cand == hn_all identity)
// ---------------------------------------------------------------------------
__global__ __launch_bounds__(256) void k_rowloss(
    const float* __restrict__ hp, const float* __restrict__ p_hn,
    const float* __restrict__ p_mb, const int* __restrict__ labels,
    float* __restrict__ gred, int* __restrict__ done,
    float* __restrict__ out, int N)
{
    int i = blockIdx.x * 256 + threadIdx.x;
    float hn_all = -BIGF, mb = -BIGF;
    #pragma unroll
    for (int s = 0; s < 16; ++s) {
        hn_all = fmaxf(hn_all, p_hn[(size_t)s * N + i]);
        mb = fmaxf(mb, p_mb[(size_t)s * N + i]);
    }
    float hpv = hp[i];
    bool valid = (labels[i] == 1) && (hpv < 1e8f) && (hn_all > -1e8f);
    float hn = (mb > hpv - 0.5f) ? mb : hn_all;
    float base = fmaxf(hn - hpv + 0.5f, 0.f);
    float wgt = (hpv < 0.6f || hn > 0.3f) ? 2.f : 1.f;
    float loss = base * wgt + 0.5f * (1.f - hpv) + 0.5f * fmaxf(hn + 0.2f, 0.f);
    float lsum = valid ? loss : 0.f;
    float lcnt = valid ? 1.f : 0.f;
    #pragma unroll
    for (int off = 32; off >= 1; off >>= 1) {
        lsum += __shfl_xor(lsum, off, 64);
        lcnt += __shfl_xor(lcnt, off, 64);
    }
    __shared__ float rs[4], rc[4];
    int wv = threadIdx.x >> 6, lane = threadIdx.x & 63;
    if (lane == 0) { rs[wv] = lsum; rc[wv] = lcnt; }
    __syncthreads();
    if (threadIdx.x == 0) {
        atomicAdd(&gred[0], rs[0] + rs[1] + rs[2] + rs[3]);
        atomicAdd(&gred[1], rc[0] + rc[1] + rc[2] + rc[3]);
        __threadfence();
        int old = atomicAdd(done, 1);
        if (old == (int)gridDim.x - 1) {
            float S = atomicAdd(&gred[0], 0.f);
            float C = atomicAdd(&gred[1], 0.f);
            out[0] = (C > 0.f) ? S / fmaxf(C, 1.f) : 0.f;
        }
    }
}

extern "C" void kernel_launch(void* const* d_in, const int* in_sizes, int n_in,
                              void* d_out, int out_size, void* d_ws, size_t ws_size,
                              hipStream_t stream)
{
    const float* emb = (const float*)d_in[0];
    const int* labels = (const int*)d_in[1];
    const int* pids = (const int*)d_in[2];
    float* out = (float*)d_out;
    int N = in_sizes[1];          // 8192

    char* ws = (char*)d_ws;
    unsigned short* normed = (unsigned short*)ws;  ws += (size_t)N * 256 * 2;  // 4 MB
    int* gpid = (int*)ws;                          ws += (size_t)N * 4;
    float* hp = (float*)ws;                        ws += (size_t)N * 4;
    float* p_hn = (float*)ws;                      ws += (size_t)N * 16 * 4;  // 512 KB
    float* p_mb = (float*)ws;                      ws += (size_t)N * 16 * 4;
    float* gred = (float*)ws;                      ws += 2 * 4;
    int* done = (int*)ws;                          ws += 4;

    k_prep<<<N / 4 + 256, 256, 0, stream>>>(emb, labels, pids, normed, gpid,
                                            hp, gred, done, N);
    k_pass2<<<(N / 128) * 4, 512, 0, stream>>>(normed, pids, gpid, hp,
                                               p_hn, p_mb, N);
    k_rowloss<<<N / 256, 256, 0, stream>>>(hp, p_hn, p_mb, labels,
                                           gred, done, out, N);
}